// Round 12
// baseline (187.330 us; speedup 1.0000x reference)
//
#include <hip/hip_runtime.h>

#define NH    8
#define DH    64
#define DIMD  512
#define NCTX  2048
#define NB    4
#define NROWS (NB * NCTX)   // 8192
#define QKVN  (3 * DIMD)    // 1536

typedef __attribute__((ext_vector_type(8))) short bf16x8;
typedef __attribute__((ext_vector_type(4))) float f32x4;

#define INV_LN2 1.44269504f
#define SCLOG   (0.125f * INV_LN2)   // folded into Q at mgemm1 epilogue

__device__ __forceinline__ unsigned short f2bits(float f) {
  unsigned u = __float_as_uint(f);
  u += 0x7fffu + ((u >> 16) & 1u);      // round-to-nearest-even
  return (unsigned short)(u >> 16);
}
__device__ __forceinline__ float bits2f(unsigned short u) {
  return __uint_as_float(((unsigned)u) << 16);
}

// ---------------- LayerNorm -> bf16: one wave per row of 512 ----------------
__global__ __launch_bounds__(256) void ln_kernel(
    const float* __restrict__ x,
    const float* __restrict__ gamma,
    const float* __restrict__ beta,
    unsigned short* __restrict__ xn) {
  const int wid  = threadIdx.x >> 6;
  const int lane = threadIdx.x & 63;
  const int row  = blockIdx.x * 4 + wid;
  const float* xr = x + (size_t)row * DIMD + lane * 8;
  float v[8];
  const float4 a = *reinterpret_cast<const float4*>(xr);
  const float4 b = *reinterpret_cast<const float4*>(xr + 4);
  v[0] = a.x; v[1] = a.y; v[2] = a.z; v[3] = a.w;
  v[4] = b.x; v[5] = b.y; v[6] = b.z; v[7] = b.w;
  float s = 0.f;
#pragma unroll
  for (int i = 0; i < 8; ++i) s += v[i];
#pragma unroll
  for (int off = 32; off; off >>= 1) s += __shfl_down(s, off);
  s = __shfl(s, 0);
  const float mu = s * (1.f / DIMD);
  float ss = 0.f;
#pragma unroll
  for (int i = 0; i < 8; ++i) { float d = v[i] - mu; ss += d * d; }
#pragma unroll
  for (int off = 32; off; off >>= 1) ss += __shfl_down(ss, off);
  ss = __shfl(ss, 0);
  const float inv = rsqrtf(ss * (1.f / DIMD) + 1e-5f);
  const float4 g0 = *reinterpret_cast<const float4*>(gamma + lane * 8);
  const float4 g1 = *reinterpret_cast<const float4*>(gamma + lane * 8 + 4);
  const float4 b0 = *reinterpret_cast<const float4*>(beta + lane * 8);
  const float4 b1 = *reinterpret_cast<const float4*>(beta + lane * 8 + 4);
  float g[8] = {g0.x, g0.y, g0.z, g0.w, g1.x, g1.y, g1.z, g1.w};
  float be[8] = {b0.x, b0.y, b0.z, b0.w, b1.x, b1.y, b1.z, b1.w};
  bf16x8 o;
#pragma unroll
  for (int i = 0; i < 8; ++i)
    o[i] = (short)f2bits((v[i] - mu) * inv * g[i] + be[i]);
  *reinterpret_cast<bf16x8*>(xn + (size_t)row * DIMD + lane * 8) = o;
}

// ---------------- Transpose + fp32->bf16: in [R][C] -> out [C][R] ----------------
__global__ __launch_bounds__(256) void tconv_kernel(
    const float* __restrict__ in, unsigned short* __restrict__ out, int R, int C) {
  __shared__ float T[64][65];
  const int r0 = blockIdx.y * 64, c0 = blockIdx.x * 64;
  const int ty = threadIdx.x >> 4, tx = threadIdx.x & 15;
#pragma unroll
  for (int i = 0; i < 4; ++i) {
    const int r = ty + i * 16;
    const float4 v = *reinterpret_cast<const float4*>(
        in + (size_t)(r0 + r) * C + c0 + tx * 4);
    T[r][tx * 4 + 0] = v.x; T[r][tx * 4 + 1] = v.y;
    T[r][tx * 4 + 2] = v.z; T[r][tx * 4 + 3] = v.w;
  }
  __syncthreads();
#pragma unroll
  for (int i = 0; i < 4; ++i) {
    const int c = ty + i * 16;
    ushort4 o;
    o.x = f2bits(T[tx * 4 + 0][c]); o.y = f2bits(T[tx * 4 + 1][c]);
    o.z = f2bits(T[tx * 4 + 2][c]); o.w = f2bits(T[tx * 4 + 3][c]);
    *reinterpret_cast<ushort4*>(out + (size_t)(c0 + c) * R + r0 + tx * 4) = o;
  }
}

// ---------------- pose-bias prep: cexp[j] = bf16(exp2(beta*pb[j]/ln2)) ----------------
__global__ __launch_bounds__(256) void pbprep_kernel(
    const float* __restrict__ pb, const float* __restrict__ betap,
    unsigned short* __restrict__ cexp) {
  const int i = blockIdx.x * 256 + threadIdx.x;
  cexp[i] = f2bits(exp2f(betap[0] * INV_LN2 * pb[i]));
}

// ---------------- V transpose + c-scale: V'[d][j] = c_j * V[j][d] ----------------
__global__ __launch_bounds__(256) void vtrans_kernel(
    const unsigned short* __restrict__ qkv,   // [NROWS, 1536] bf16
    const unsigned short* __restrict__ cexp,  // [NB*NCTX] bf16
    unsigned short* __restrict__ vt) {        // [NB*NH*64][2048] bf16
  __shared__ unsigned short T[64][68];
  const int jt = blockIdx.x, hi = blockIdx.y, bi = blockIdx.z;
  const int ty = threadIdx.x >> 4, tx = threadIdx.x & 15;
  const int j0 = jt * 64;
#pragma unroll
  for (int i = 0; i < 4; ++i) {
    const int j = ty + i * 16;
    const ushort4 v = *reinterpret_cast<const ushort4*>(
        qkv + (size_t)(bi * NCTX + j0 + j) * QKVN + 2 * DIMD + hi * DH + tx * 4);
    T[j][tx * 4 + 0] = v.x; T[j][tx * 4 + 1] = v.y;
    T[j][tx * 4 + 2] = v.z; T[j][tx * 4 + 3] = v.w;
  }
  const ushort4 cv = *reinterpret_cast<const ushort4*>(cexp + bi * NCTX + j0 + tx * 4);
  const float c0 = bits2f(cv.x), c1 = bits2f(cv.y), c2 = bits2f(cv.z), c3 = bits2f(cv.w);
  __syncthreads();
#pragma unroll
  for (int i = 0; i < 4; ++i) {
    const int d = ty + i * 16;
    ushort4 o;
    o.x = f2bits(bits2f(T[tx * 4 + 0][d]) * c0);
    o.y = f2bits(bits2f(T[tx * 4 + 1][d]) * c1);
    o.z = f2bits(bits2f(T[tx * 4 + 2][d]) * c2);
    o.w = f2bits(bits2f(T[tx * 4 + 3][d]) * c3);
    *reinterpret_cast<ushort4*>(
        vt + ((size_t)(bi * NH + hi) * DH + d) * NCTX + j0 + tx * 4) = o;
  }
}

// ---------------- MFMA GEMM, register-prefetch pipelined ----------------
__device__ __forceinline__ void storeC(float* C, size_t idx, float v) { C[idx] = v; }
__device__ __forceinline__ void storeC(unsigned short* C, size_t idx, float v) { C[idx] = f2bits(v); }

template <typename CT, bool QS>
__global__ __launch_bounds__(256) void mgemm_kernel(
    const unsigned short* __restrict__ A, const unsigned short* __restrict__ Bt,
    CT* __restrict__ C, int M, int N, int K) {
  __shared__ __align__(16) unsigned short As[128][72];
  __shared__ __align__(16) unsigned short Bs[128][72];
  const int tid  = threadIdx.x;
  const int wave = tid >> 6, lane = tid & 63;
  const int quad = lane >> 4, l16 = lane & 15;
  const int wr = wave >> 1, wc = wave & 1;
  const int tm0 = blockIdx.y * 128, tn0 = blockIdx.x * 128;
  const int srow = tid >> 3;
  const int schunk = (tid & 7) * 8;
  f32x4 acc[4][4];
#pragma unroll
  for (int i = 0; i < 4; ++i)
#pragma unroll
    for (int j = 0; j < 4; ++j) acc[i][j] = (f32x4){0.f, 0.f, 0.f, 0.f};

  bf16x8 ra[4], rb[4];
#pragma unroll
  for (int p = 0; p < 4; ++p) {
    const int r = srow + p * 32;
    ra[p] = *reinterpret_cast<const bf16x8*>(A + (size_t)(tm0 + r) * K + schunk);
    rb[p] = *reinterpret_cast<const bf16x8*>(Bt + (size_t)(tn0 + r) * K + schunk);
  }
  for (int k0 = 0; k0 < K; k0 += 64) {
#pragma unroll
    for (int p = 0; p < 4; ++p) {
      const int r = srow + p * 32;
      *reinterpret_cast<bf16x8*>(&As[r][schunk]) = ra[p];
      *reinterpret_cast<bf16x8*>(&Bs[r][schunk]) = rb[p];
    }
    __syncthreads();
    if (k0 + 64 < K) {      // prefetch next K-slab; latency hidden behind MFMAs
#pragma unroll
      for (int p = 0; p < 4; ++p) {
        const int r = srow + p * 32;
        ra[p] = *reinterpret_cast<const bf16x8*>(A + (size_t)(tm0 + r) * K + k0 + 64 + schunk);
        rb[p] = *reinterpret_cast<const bf16x8*>(Bt + (size_t)(tn0 + r) * K + k0 + 64 + schunk);
      }
    }
#pragma unroll
    for (int kc = 0; kc < 2; ++kc) {
      const int kk = kc * 32 + quad * 8;
      bf16x8 af[4], bfr[4];
#pragma unroll
      for (int i = 0; i < 4; ++i)
        af[i] = *reinterpret_cast<const bf16x8*>(&As[wr * 64 + i * 16 + l16][kk]);
#pragma unroll
      for (int j = 0; j < 4; ++j)
        bfr[j] = *reinterpret_cast<const bf16x8*>(&Bs[wc * 64 + j * 16 + l16][kk]);
#pragma unroll
      for (int i = 0; i < 4; ++i)
#pragma unroll
        for (int j = 0; j < 4; ++j)
          acc[i][j] = __builtin_amdgcn_mfma_f32_16x16x32_bf16(af[i], bfr[j], acc[i][j], 0, 0, 0);
    }
    __syncthreads();
  }
#pragma unroll
  for (int j = 0; j < 4; ++j) {
    const int col = tn0 + wc * 64 + j * 16 + l16;
    const float scl = (QS && col < DIMD) ? SCLOG : 1.0f;
#pragma unroll
    for (int i = 0; i < 4; ++i)
#pragma unroll
      for (int r = 0; r < 4; ++r)
        storeC(C, (size_t)(tm0 + wr * 64 + i * 16 + quad * 4 + r) * N + col,
               acc[i][j][r] * scl);
  }
}

// ---------------- MFMA flash attention: 128-query block, 2x2 wave split ----------------
// Wave = (query-half wq: 64 q, key-half wk: 32 k). DS-read insts/score = 0.28/Mq —
// Mq=64 halves LDS traffic vs round 11. Q frags direct from global; dedicated regions.
__global__ __launch_bounds__(256, 2) void fattn_kernel(
    const unsigned short* __restrict__ qkv,   // [NROWS, 1536] bf16 (Q pre-scaled by SCLOG)
    const unsigned short* __restrict__ vtg,   // [NB*NH*64][2048] bf16 (c-scaled V^T)
    const unsigned short* __restrict__ cexp,  // [NB*NCTX] bf16
    unsigned short* __restrict__ out) {       // [NROWS, 512] bf16
  // LDS layout (shorts): [0,10240)     P (4 waves x [64][40])
  //                      [10240,14848) Kl[64][72]
  //                      [14848,20608) Vt[80][72] (row 64 = c_j; rows 65..79 = 0)
  //                      [20608,28800) Ob bf16 [128][64]
  //                      [28800,29312) lb fp32 [256]
  __shared__ __align__(16) unsigned short lds[29312];
  unsigned short (*Kl)[72] = (unsigned short (*)[72])(lds + 10240);
  unsigned short (*Vt)[72] = (unsigned short (*)[72])(lds + 14848);
  unsigned short* Ob = lds + 20608;
  float* lb = (float*)(lds + 28800);

  const int qt = blockIdx.x, hi = blockIdx.y, bi = blockIdx.z;
  const int tid  = threadIdx.x;
  const int wave = tid >> 6, lane = tid & 63;
  const int quad = lane >> 4, l16 = lane & 15;
  const int wq = wave & 1, wk = wave >> 1;
  unsigned short* Pw = lds + wave * 2560;    // [64][40]
  const int qrow0 = qt * 128;
  const unsigned short* base  = qkv + (size_t)bi * NCTX * QKVN + hi * DH;
  const unsigned short* vbase = vtg + (size_t)(bi * NH + hi) * DH * NCTX;
  const unsigned short* cbase = cexp + (size_t)bi * NCTX;
  const int sr = tid >> 2;            // staging row 0..63
  const int sc4 = (tid & 3) * 16;     // staging col base (shorts)

  // ---- Q B-frags straight from global (one-time, 64B-line aligned rows) ----
  bf16x8 qf[4][2];
#pragma unroll
  for (int u = 0; u < 4; ++u)
#pragma unroll
    for (int h = 0; h < 2; ++h)
      qf[u][h] = *reinterpret_cast<const bf16x8*>(
          base + (size_t)(qrow0 + wq * 64 + u * 16 + l16) * QKVN + h * 32 + quad * 8);
  // ---- zero Vt rows 65..79 (read-only thereafter) ----
  if (tid < 135) {
    const uint4 z = {0u, 0u, 0u, 0u};
    *reinterpret_cast<uint4*>(&Vt[65 + tid / 9][(tid % 9) * 8]) = z;
  }
  // ---- prefetch + publish tile 0 ----
  bf16x8 pk0, pk1, pv0, pv1; ushort4 pc;
  {
    const unsigned short* kr = base + (size_t)sr * QKVN + DIMD + sc4;
    pk0 = *reinterpret_cast<const bf16x8*>(kr);
    pk1 = *reinterpret_cast<const bf16x8*>(kr + 8);
    const unsigned short* vr = vbase + (size_t)sr * NCTX + sc4;
    pv0 = *reinterpret_cast<const bf16x8*>(vr);
    pv1 = *reinterpret_cast<const bf16x8*>(vr + 8);
    if (tid < 16) pc = *reinterpret_cast<const ushort4*>(cbase + tid * 4);
    *reinterpret_cast<bf16x8*>(&Kl[sr][sc4])     = pk0;
    *reinterpret_cast<bf16x8*>(&Kl[sr][sc4 + 8]) = pk1;
    *reinterpret_cast<bf16x8*>(&Vt[sr][sc4])     = pv0;
    *reinterpret_cast<bf16x8*>(&Vt[sr][sc4 + 8]) = pv1;
    if (tid < 16) *reinterpret_cast<ushort4*>(&Vt[64][tid * 4]) = pc;
  }
  __syncthreads();

  f32x4 O[4][4], accl[4];
#pragma unroll
  for (int u = 0; u < 4; ++u) {
    accl[u] = (f32x4){0.f, 0.f, 0.f, 0.f};
#pragma unroll
    for (int s = 0; s < 4; ++s) O[u][s] = (f32x4){0.f, 0.f, 0.f, 0.f};
  }

  for (int kt = 0; kt < 32; ++kt) {
    // ---- prefetch next tile ----
    if (kt < 31) {
      const int krow1 = (kt + 1) * 64;
      const unsigned short* kr = base + (size_t)(krow1 + sr) * QKVN + DIMD + sc4;
      pk0 = *reinterpret_cast<const bf16x8*>(kr);
      pk1 = *reinterpret_cast<const bf16x8*>(kr + 8);
      const unsigned short* vr = vbase + (size_t)sr * NCTX + krow1 + sc4;
      pv0 = *reinterpret_cast<const bf16x8*>(vr);
      pv1 = *reinterpret_cast<const bf16x8*>(vr + 8);
      if (tid < 16) pc = *reinterpret_cast<const ushort4*>(cbase + krow1 + tid * 4);
    }
    // ---- S^T = K Q^T on wave's 32 keys x 64 queries ----
#pragma unroll
    for (int t = 0; t < 2; ++t) {
      const bf16x8 kf0 = *reinterpret_cast<const bf16x8*>(
          &Kl[wk * 32 + t * 16 + l16][quad * 8]);
      const bf16x8 kf1 = *reinterpret_cast<const bf16x8*>(
          &Kl[wk * 32 + t * 16 + l16][32 + quad * 8]);
#pragma unroll
      for (int u = 0; u < 4; ++u) {
        f32x4 acc = (f32x4){0.f, 0.f, 0.f, 0.f};
        acc = __builtin_amdgcn_mfma_f32_16x16x32_bf16(kf0, qf[u][0], acc, 0, 0, 0);
        acc = __builtin_amdgcn_mfma_f32_16x16x32_bf16(kf1, qf[u][1], acc, 0, 0, 0);
        // ---- P = exp2(S^T): pack 4 consecutive local keys -> one b64 write ----
        const unsigned u0 = __float_as_uint(exp2f(acc[0])) + 0x8000u;
        const unsigned u1 = __float_as_uint(exp2f(acc[1])) + 0x8000u;
        const unsigned u2 = __float_as_uint(exp2f(acc[2])) + 0x8000u;
        const unsigned u3 = __float_as_uint(exp2f(acc[3])) + 0x8000u;
        uint2 pw;
        pw.x = __builtin_amdgcn_perm(u1, u0, 0x07060302u);
        pw.y = __builtin_amdgcn_perm(u3, u2, 0x07060302u);
        *reinterpret_cast<uint2*>(&Pw[(u * 16 + l16) * 40 + t * 16 + quad * 4]) = pw;
      }
    }
    // ---- O += P V' over wave's 32 keys; denominator via c-row ----
    {
      const bf16x8 cf = *reinterpret_cast<const bf16x8*>(
          &Vt[64 + l16][wk * 32 + quad * 8]);
      bf16x8 bv[4];
#pragma unroll
      for (int s = 0; s < 4; ++s)
        bv[s] = *reinterpret_cast<const bf16x8*>(
            &Vt[s * 16 + l16][wk * 32 + quad * 8]);
#pragma unroll
      for (int u = 0; u < 4; ++u) {
        const bf16x8 pf = *reinterpret_cast<const bf16x8*>(
            &Pw[(u * 16 + l16) * 40 + quad * 8]);
#pragma unroll
        for (int s = 0; s < 4; ++s)
          O[u][s] = __builtin_amdgcn_mfma_f32_16x16x32_bf16(pf, bv[s], O[u][s], 0, 0, 0);
        accl[u] = __builtin_amdgcn_mfma_f32_16x16x32_bf16(pf, cf, accl[u], 0, 0, 0);
      }
    }
    // ---- publish prefetched tile ----
    if (kt < 31) {
      __syncthreads();
      *reinterpret_cast<bf16x8*>(&Kl[sr][sc4])     = pk0;
      *reinterpret_cast<bf16x8*>(&Kl[sr][sc4 + 8]) = pk1;
      *reinterpret_cast<bf16x8*>(&Vt[sr][sc4])     = pv0;
      *reinterpret_cast<bf16x8*>(&Vt[sr][sc4 + 8]) = pv1;
      if (tid < 16) *reinterpret_cast<ushort4*>(&Vt[64][tid * 4]) = pc;
      __syncthreads();
    }
  }
  // ---- combine key-halves via dedicated Ob (bf16) + lb (fp32) ----
  // accl is a D-tile: c-row product sits in column 0 -> lanes l16==0, rows quad*4+r.
  __syncthreads();
  if (wk == 1) {
#pragma unroll
    for (int u = 0; u < 4; ++u) {
#pragma unroll
      for (int s = 0; s < 4; ++s)
#pragma unroll
        for (int r = 0; r < 4; ++r)
          Ob[(wq * 64 + u * 16 + quad * 4 + r) * 64 + s * 16 + l16] = f2bits(O[u][s][r]);
      if (l16 == 0)
#pragma unroll
        for (int r = 0; r < 4; ++r)
          lb[128 + wq * 64 + u * 16 + quad * 4 + r] = accl[u][r];
    }
  } else {
#pragma unroll
    for (int u = 0; u < 4; ++u)
      if (l16 == 0)
#pragma unroll
        for (int r = 0; r < 4; ++r)
          lb[wq * 64 + u * 16 + quad * 4 + r] = accl[u][r];
  }
  __syncthreads();
  if (wk == 0) {
#pragma unroll
    for (int u = 0; u < 4; ++u)
#pragma unroll
      for (int r = 0; r < 4; ++r) {
        const int ql = wq * 64 + u * 16 + quad * 4 + r;
        const float linv = 1.f / (lb[ql] + lb[128 + ql]);
        const size_t orow = ((size_t)bi * NCTX + qrow0 + ql) * DIMD + hi * DH;
#pragma unroll
        for (int s = 0; s < 4; ++s)
          out[orow + s * 16 + l16] =
              f2bits((O[u][s][r] + bits2f(Ob[ql * 64 + s * 16 + l16])) * linv);
      }
  }
}

extern "C" void kernel_launch(void* const* d_in, const int* in_sizes, int n_in,
                              void* d_out, int out_size, void* d_ws, size_t ws_size,
                              hipStream_t stream) {
  const float* x     = (const float*)d_in[0];
  const float* pose  = (const float*)d_in[1];
  const float* gam   = (const float*)d_in[2];
  const float* bet   = (const float*)d_in[3];
  const float* wqkv  = (const float*)d_in[4];
  const float* wout  = (const float*)d_in[5];
  const float* betap = (const float*)d_in[6];
  float* out = (float*)d_out;

  unsigned short* xn    = (unsigned short*)d_ws;             // 8 MB (reused as aout)
  unsigned short* qkvb  = xn + (size_t)NROWS * DIMD;         // 24 MB
  unsigned short* wqkvT = qkvb + (size_t)NROWS * QKVN;       // 1.5 MB
  unsigned short* woutT = wqkvT + (size_t)QKVN * DIMD;       // 0.5 MB
  unsigned short* vtg   = woutT + (size_t)DIMD * DIMD;       // 8 MB  c-scaled V^T
  unsigned short* cexp  = vtg + (size_t)NB * NH * DH * NCTX; // 16 KB
  unsigned short* aout  = xn;                                // alias: xn dead after GEMM1

  ln_kernel<<<NROWS / 4, 256, 0, stream>>>(x, gam, bet, xn);
  tconv_kernel<<<dim3(QKVN / 64, DIMD / 64), 256, 0, stream>>>(wqkv, wqkvT, DIMD, QKVN);
  tconv_kernel<<<dim3(DIMD / 64, DIMD / 64), 256, 0, stream>>>(wout, woutT, DIMD, DIMD);
  pbprep_kernel<<<NROWS / 256, 256, 0, stream>>>(pose, betap, cexp);
  mgemm_kernel<unsigned short, true><<<dim3(QKVN / 128, NROWS / 128), 256, 0, stream>>>(
      xn, wqkvT, qkvb, NROWS, QKVN, DIMD);
  vtrans_kernel<<<dim3(NCTX / 64, NH, NB), 256, 0, stream>>>(qkvb, cexp, vtg);
  fattn_kernel<<<dim3(NCTX / 128, NH, NB), 256, 0, stream>>>(qkvb, vtg, cexp, aout);
  mgemm_kernel<float, false><<<dim3(DIMD / 128, NROWS / 128), 256, 0, stream>>>(
      aout, woutT, out, NROWS, DIMD, DIMD);
}

// Round 13
// 176.525 us; speedup vs baseline: 1.0612x; 1.0612x over previous
//
#include <hip/hip_runtime.h>

#define NH    8
#define DH    64
#define DIMD  512
#define NCTX  2048
#define NB    4
#define NROWS (NB * NCTX)   // 8192
#define QKVN  (3 * DIMD)    // 1536

typedef __attribute__((ext_vector_type(8))) short bf16x8;
typedef __attribute__((ext_vector_type(4))) float f32x4;

#define INV_LN2 1.44269504f
#define SCLOG   (0.125f * INV_LN2)   // folded into Q at mgemm1 epilogue

__device__ __forceinline__ unsigned short f2bits(float f) {
  unsigned u = __float_as_uint(f);
  u += 0x7fffu + ((u >> 16) & 1u);      // round-to-nearest-even
  return (unsigned short)(u >> 16);
}
__device__ __forceinline__ float bits2f(unsigned short u) {
  return __uint_as_float(((unsigned)u) << 16);
}

// ---------------- LayerNorm -> bf16: one wave per row of 512 ----------------
__global__ __launch_bounds__(256) void ln_kernel(
    const float* __restrict__ x,
    const float* __restrict__ gamma,
    const float* __restrict__ beta,
    unsigned short* __restrict__ xn) {
  const int wid  = threadIdx.x >> 6;
  const int lane = threadIdx.x & 63;
  const int row  = blockIdx.x * 4 + wid;
  const float* xr = x + (size_t)row * DIMD + lane * 8;
  float v[8];
  const float4 a = *reinterpret_cast<const float4*>(xr);
  const float4 b = *reinterpret_cast<const float4*>(xr + 4);
  v[0] = a.x; v[1] = a.y; v[2] = a.z; v[3] = a.w;
  v[4] = b.x; v[5] = b.y; v[6] = b.z; v[7] = b.w;
  float s = 0.f;
#pragma unroll
  for (int i = 0; i < 8; ++i) s += v[i];
#pragma unroll
  for (int off = 32; off; off >>= 1) s += __shfl_down(s, off);
  s = __shfl(s, 0);
  const float mu = s * (1.f / DIMD);
  float ss = 0.f;
#pragma unroll
  for (int i = 0; i < 8; ++i) { float d = v[i] - mu; ss += d * d; }
#pragma unroll
  for (int off = 32; off; off >>= 1) ss += __shfl_down(ss, off);
  ss = __shfl(ss, 0);
  const float inv = rsqrtf(ss * (1.f / DIMD) + 1e-5f);
  const float4 g0 = *reinterpret_cast<const float4*>(gamma + lane * 8);
  const float4 g1 = *reinterpret_cast<const float4*>(gamma + lane * 8 + 4);
  const float4 b0 = *reinterpret_cast<const float4*>(beta + lane * 8);
  const float4 b1 = *reinterpret_cast<const float4*>(beta + lane * 8 + 4);
  float g[8] = {g0.x, g0.y, g0.z, g0.w, g1.x, g1.y, g1.z, g1.w};
  float be[8] = {b0.x, b0.y, b0.z, b0.w, b1.x, b1.y, b1.z, b1.w};
  bf16x8 o;
#pragma unroll
  for (int i = 0; i < 8; ++i)
    o[i] = (short)f2bits((v[i] - mu) * inv * g[i] + be[i]);
  *reinterpret_cast<bf16x8*>(xn + (size_t)row * DIMD + lane * 8) = o;
}

// ---------------- Fused transpose+cvt for BOTH weights (z picks matrix) ----------------
// in [R][C] fp32 -> out [C][R] bf16.  z=0: wqkv (C=1536), z=1: wout (C=512).
__global__ __launch_bounds__(256) void tconv_kernel(
    const float* __restrict__ in0, unsigned short* __restrict__ out0,
    const float* __restrict__ in1, unsigned short* __restrict__ out1) {
  const int z = blockIdx.z;
  const int C = z ? DIMD : QKVN;
  if (z && blockIdx.x >= DIMD / 64) return;
  const float* in = z ? in1 : in0;
  unsigned short* out = z ? out1 : out0;
  __shared__ float T[64][65];
  const int r0 = blockIdx.y * 64, c0 = blockIdx.x * 64;
  const int ty = threadIdx.x >> 4, tx = threadIdx.x & 15;
#pragma unroll
  for (int i = 0; i < 4; ++i) {
    const int r = ty + i * 16;
    const float4 v = *reinterpret_cast<const float4*>(
        in + (size_t)(r0 + r) * C + c0 + tx * 4);
    T[r][tx * 4 + 0] = v.x; T[r][tx * 4 + 1] = v.y;
    T[r][tx * 4 + 2] = v.z; T[r][tx * 4 + 3] = v.w;
  }
  __syncthreads();
#pragma unroll
  for (int i = 0; i < 4; ++i) {
    const int c = ty + i * 16;
    ushort4 o;
    o.x = f2bits(T[tx * 4 + 0][c]); o.y = f2bits(T[tx * 4 + 1][c]);
    o.z = f2bits(T[tx * 4 + 2][c]); o.w = f2bits(T[tx * 4 + 3][c]);
    *reinterpret_cast<ushort4*>(out + (size_t)(c0 + c) * DIMD + r0 + tx * 4) = o;
  }
}

// ---------------- V transpose + c-scale (pbprep folded in) ----------------
// c_j = bf16(exp2(beta*pb_j/ln2)); V'[d][j] = c_j * V[j][d]; hi==0 blocks emit cexp.
__global__ __launch_bounds__(256) void vtrans_kernel(
    const unsigned short* __restrict__ qkv,   // [NROWS, 1536] bf16
    const float* __restrict__ pb,             // [NB*NCTX] fp32
    const float* __restrict__ betap,
    unsigned short* __restrict__ cexp,        // [NB*NCTX] bf16 (out)
    unsigned short* __restrict__ vt) {        // [NB*NH*64][2048] bf16
  __shared__ unsigned short T[64][68];
  const int jt = blockIdx.x, hi = blockIdx.y, bi = blockIdx.z;
  const int ty = threadIdx.x >> 4, tx = threadIdx.x & 15;
  const int j0 = jt * 64;
#pragma unroll
  for (int i = 0; i < 4; ++i) {
    const int j = ty + i * 16;
    const ushort4 v = *reinterpret_cast<const ushort4*>(
        qkv + (size_t)(bi * NCTX + j0 + j) * QKVN + 2 * DIMD + hi * DH + tx * 4);
    T[j][tx * 4 + 0] = v.x; T[j][tx * 4 + 1] = v.y;
    T[j][tx * 4 + 2] = v.z; T[j][tx * 4 + 3] = v.w;
  }
  const float bl2 = betap[0] * INV_LN2;
  const float4 pv = *reinterpret_cast<const float4*>(pb + bi * NCTX + j0 + tx * 4);
  ushort4 cb;   // bf16-rounded c (matches round-11 numerics exactly)
  cb.x = f2bits(exp2f(bl2 * pv.x)); cb.y = f2bits(exp2f(bl2 * pv.y));
  cb.z = f2bits(exp2f(bl2 * pv.z)); cb.w = f2bits(exp2f(bl2 * pv.w));
  if (hi == 0 && ty == 0)
    *reinterpret_cast<ushort4*>(cexp + bi * NCTX + j0 + tx * 4) = cb;
  const float c0 = bits2f(cb.x), c1 = bits2f(cb.y), c2 = bits2f(cb.z), c3 = bits2f(cb.w);
  __syncthreads();
#pragma unroll
  for (int i = 0; i < 4; ++i) {
    const int d = ty + i * 16;
    ushort4 o;
    o.x = f2bits(bits2f(T[tx * 4 + 0][d]) * c0);
    o.y = f2bits(bits2f(T[tx * 4 + 1][d]) * c1);
    o.z = f2bits(bits2f(T[tx * 4 + 2][d]) * c2);
    o.w = f2bits(bits2f(T[tx * 4 + 3][d]) * c3);
    *reinterpret_cast<ushort4*>(
        vt + ((size_t)(bi * NH + hi) * DH + d) * NCTX + j0 + tx * 4) = o;
  }
}

// ---------------- MFMA GEMM, register-prefetch pipelined ----------------
__device__ __forceinline__ void storeC(float* C, size_t idx, float v) { C[idx] = v; }
__device__ __forceinline__ void storeC(unsigned short* C, size_t idx, float v) { C[idx] = f2bits(v); }

template <typename CT, bool QS>
__global__ __launch_bounds__(256) void mgemm_kernel(
    const unsigned short* __restrict__ A, const unsigned short* __restrict__ Bt,
    CT* __restrict__ C, int M, int N, int K) {
  __shared__ __align__(16) unsigned short As[128][72];
  __shared__ __align__(16) unsigned short Bs[128][72];
  const int tid  = threadIdx.x;
  const int wave = tid >> 6, lane = tid & 63;
  const int quad = lane >> 4, l16 = lane & 15;
  const int wr = wave >> 1, wc = wave & 1;
  const int tm0 = blockIdx.y * 128, tn0 = blockIdx.x * 128;
  const int srow = tid >> 3;
  const int schunk = (tid & 7) * 8;
  f32x4 acc[4][4];
#pragma unroll
  for (int i = 0; i < 4; ++i)
#pragma unroll
    for (int j = 0; j < 4; ++j) acc[i][j] = (f32x4){0.f, 0.f, 0.f, 0.f};

  bf16x8 ra[4], rb[4];
#pragma unroll
  for (int p = 0; p < 4; ++p) {
    const int r = srow + p * 32;
    ra[p] = *reinterpret_cast<const bf16x8*>(A + (size_t)(tm0 + r) * K + schunk);
    rb[p] = *reinterpret_cast<const bf16x8*>(Bt + (size_t)(tn0 + r) * K + schunk);
  }
  for (int k0 = 0; k0 < K; k0 += 64) {
#pragma unroll
    for (int p = 0; p < 4; ++p) {
      const int r = srow + p * 32;
      *reinterpret_cast<bf16x8*>(&As[r][schunk]) = ra[p];
      *reinterpret_cast<bf16x8*>(&Bs[r][schunk]) = rb[p];
    }
    __syncthreads();
    if (k0 + 64 < K) {      // prefetch next K-slab; latency hidden behind MFMAs
#pragma unroll
      for (int p = 0; p < 4; ++p) {
        const int r = srow + p * 32;
        ra[p] = *reinterpret_cast<const bf16x8*>(A + (size_t)(tm0 + r) * K + k0 + 64 + schunk);
        rb[p] = *reinterpret_cast<const bf16x8*>(Bt + (size_t)(tn0 + r) * K + k0 + 64 + schunk);
      }
    }
#pragma unroll
    for (int kc = 0; kc < 2; ++kc) {
      const int kk = kc * 32 + quad * 8;
      bf16x8 af[4], bfr[4];
#pragma unroll
      for (int i = 0; i < 4; ++i)
        af[i] = *reinterpret_cast<const bf16x8*>(&As[wr * 64 + i * 16 + l16][kk]);
#pragma unroll
      for (int j = 0; j < 4; ++j)
        bfr[j] = *reinterpret_cast<const bf16x8*>(&Bs[wc * 64 + j * 16 + l16][kk]);
#pragma unroll
      for (int i = 0; i < 4; ++i)
#pragma unroll
        for (int j = 0; j < 4; ++j)
          acc[i][j] = __builtin_amdgcn_mfma_f32_16x16x32_bf16(af[i], bfr[j], acc[i][j], 0, 0, 0);
    }
    __syncthreads();
  }
#pragma unroll
  for (int j = 0; j < 4; ++j) {
    const int col = tn0 + wc * 64 + j * 16 + l16;
    const float scl = (QS && col < DIMD) ? SCLOG : 1.0f;
#pragma unroll
    for (int i = 0; i < 4; ++i)
#pragma unroll
      for (int r = 0; r < 4; ++r)
        storeC(C, (size_t)(tm0 + wr * 64 + i * 16 + quad * 4 + r) * N + col,
               acc[i][j][r] * scl);
  }
}

// ---------------- MFMA flash attention: 2x2 wave split (round-11 config) ----------------
// 64-query block; wave = (query-half: 32q, key-half: 32k). 4 blocks/CU — overlap-bound
// balance point (round 12 showed Mq=64 halves DS but loses occupancy: neutral).
__global__ __launch_bounds__(256, 4) void fattn_kernel(
    const unsigned short* __restrict__ qkv,   // [NROWS, 1536] bf16 (Q pre-scaled by SCLOG)
    const unsigned short* __restrict__ vtg,   // [NB*NH*64][2048] bf16 (c-scaled V^T)
    const unsigned short* __restrict__ cexp,  // [NB*NCTX] bf16
    unsigned short* __restrict__ out) {       // [NROWS, 512] bf16
  // LDS layout (shorts): [0,5120) P (4 waves x [32][40])
  //                      [5120,9728)   Kl[64][72]
  //                      [9728,15488)  Vt[80][72] (row 64 = c_j; rows 65..79 = 0)
  //                      [15488,19584) Ob bf16 [64][64]
  //                      [19584,19840) lb fp32 [128]
  __shared__ __align__(16) unsigned short lds[19840];
  unsigned short (*Kl)[72] = (unsigned short (*)[72])(lds + 5120);
  unsigned short (*Vt)[72] = (unsigned short (*)[72])(lds + 9728);
  unsigned short* Ob = lds + 15488;
  float* lb = (float*)(lds + 19584);

  const int qt = blockIdx.x, hi = blockIdx.y, bi = blockIdx.z;
  const int tid  = threadIdx.x;
  const int wave = tid >> 6, lane = tid & 63;
  const int quad = lane >> 4, l16 = lane & 15;
  const int wq = wave & 1, wk = wave >> 1;
  unsigned short* Pw = lds + wave * 1280;    // [32][40]
  const int qrow0 = qt * 64;
  const unsigned short* base  = qkv + (size_t)bi * NCTX * QKVN + hi * DH;
  const unsigned short* vbase = vtg + (size_t)(bi * NH + hi) * DH * NCTX;
  const unsigned short* cbase = cexp + (size_t)bi * NCTX;
  const int sr = tid >> 2;            // staging row 0..63
  const int sc4 = (tid & 3) * 16;     // staging col base (shorts)

  // ---- Q B-frags straight from global (one-time, 64B-line aligned rows) ----
  bf16x8 qf[2][2];
#pragma unroll
  for (int u = 0; u < 2; ++u)
#pragma unroll
    for (int h = 0; h < 2; ++h)
      qf[u][h] = *reinterpret_cast<const bf16x8*>(
          base + (size_t)(qrow0 + wq * 32 + u * 16 + l16) * QKVN + h * 32 + quad * 8);
  // ---- zero Vt rows 65..79 (read-only thereafter) ----
  if (tid < 135) {
    const uint4 z = {0u, 0u, 0u, 0u};
    *reinterpret_cast<uint4*>(&Vt[65 + tid / 9][(tid % 9) * 8]) = z;
  }
  // ---- prefetch + publish tile 0 ----
  bf16x8 pk0, pk1, pv0, pv1; ushort4 pc;
  {
    const unsigned short* kr = base + (size_t)sr * QKVN + DIMD + sc4;
    pk0 = *reinterpret_cast<const bf16x8*>(kr);
    pk1 = *reinterpret_cast<const bf16x8*>(kr + 8);
    const unsigned short* vr = vbase + (size_t)sr * NCTX + sc4;
    pv0 = *reinterpret_cast<const bf16x8*>(vr);
    pv1 = *reinterpret_cast<const bf16x8*>(vr + 8);
    if (tid < 16) pc = *reinterpret_cast<const ushort4*>(cbase + tid * 4);
    *reinterpret_cast<bf16x8*>(&Kl[sr][sc4])     = pk0;
    *reinterpret_cast<bf16x8*>(&Kl[sr][sc4 + 8]) = pk1;
    *reinterpret_cast<bf16x8*>(&Vt[sr][sc4])     = pv0;
    *reinterpret_cast<bf16x8*>(&Vt[sr][sc4 + 8]) = pv1;
    if (tid < 16) *reinterpret_cast<ushort4*>(&Vt[64][tid * 4]) = pc;
  }
  __syncthreads();

  f32x4 O[2][4], accl[2];
#pragma unroll
  for (int u = 0; u < 2; ++u) {
    accl[u] = (f32x4){0.f, 0.f, 0.f, 0.f};
#pragma unroll
    for (int s = 0; s < 4; ++s) O[u][s] = (f32x4){0.f, 0.f, 0.f, 0.f};
  }

  for (int kt = 0; kt < 32; ++kt) {
    // ---- prefetch next tile ----
    if (kt < 31) {
      const int krow1 = (kt + 1) * 64;
      const unsigned short* kr = base + (size_t)(krow1 + sr) * QKVN + DIMD + sc4;
      pk0 = *reinterpret_cast<const bf16x8*>(kr);
      pk1 = *reinterpret_cast<const bf16x8*>(kr + 8);
      const unsigned short* vr = vbase + (size_t)sr * NCTX + krow1 + sc4;
      pv0 = *reinterpret_cast<const bf16x8*>(vr);
      pv1 = *reinterpret_cast<const bf16x8*>(vr + 8);
      if (tid < 16) pc = *reinterpret_cast<const ushort4*>(cbase + krow1 + tid * 4);
    }
    // ---- S^T = K Q^T on wave's 32 keys x 32 queries ----
    f32x4 sfr[2][2];   // [t key-sub][u query-sub]
#pragma unroll
    for (int t = 0; t < 2; ++t) {
      const bf16x8 kf0 = *reinterpret_cast<const bf16x8*>(
          &Kl[wk * 32 + t * 16 + l16][quad * 8]);
      const bf16x8 kf1 = *reinterpret_cast<const bf16x8*>(
          &Kl[wk * 32 + t * 16 + l16][32 + quad * 8]);
#pragma unroll
      for (int u = 0; u < 2; ++u) {
        f32x4 acc = (f32x4){0.f, 0.f, 0.f, 0.f};
        acc = __builtin_amdgcn_mfma_f32_16x16x32_bf16(kf0, qf[u][0], acc, 0, 0, 0);
        acc = __builtin_amdgcn_mfma_f32_16x16x32_bf16(kf1, qf[u][1], acc, 0, 0, 0);
        sfr[t][u] = acc;
      }
    }
    // ---- P = exp2(S): pack 4 consecutive local keys -> one b64 write ----
#pragma unroll
    for (int t = 0; t < 2; ++t)
#pragma unroll
      for (int u = 0; u < 2; ++u) {
        const unsigned u0 = __float_as_uint(exp2f(sfr[t][u][0])) + 0x8000u;
        const unsigned u1 = __float_as_uint(exp2f(sfr[t][u][1])) + 0x8000u;
        const unsigned u2 = __float_as_uint(exp2f(sfr[t][u][2])) + 0x8000u;
        const unsigned u3 = __float_as_uint(exp2f(sfr[t][u][3])) + 0x8000u;
        uint2 pw;
        pw.x = __builtin_amdgcn_perm(u1, u0, 0x07060302u);
        pw.y = __builtin_amdgcn_perm(u3, u2, 0x07060302u);
        *reinterpret_cast<uint2*>(&Pw[(u * 16 + l16) * 40 + t * 16 + quad * 4]) = pw;
      }
    // ---- O += P V' over wave's keys; denominator via c-row ----
    {
      const bf16x8 cf = *reinterpret_cast<const bf16x8*>(
          &Vt[64 + l16][wk * 32 + quad * 8]);
#pragma unroll
      for (int u = 0; u < 2; ++u) {
        const bf16x8 pf = *reinterpret_cast<const bf16x8*>(
            &Pw[(u * 16 + l16) * 40 + quad * 8]);
#pragma unroll
        for (int s = 0; s < 4; ++s) {
          const bf16x8 bv = *reinterpret_cast<const bf16x8*>(
              &Vt[s * 16 + l16][wk * 32 + quad * 8]);
          O[u][s] = __builtin_amdgcn_mfma_f32_16x16x32_bf16(pf, bv, O[u][s], 0, 0, 0);
        }
        accl[u] = __builtin_amdgcn_mfma_f32_16x16x32_bf16(pf, cf, accl[u], 0, 0, 0);
      }
    }
    // ---- publish prefetched tile ----
    if (kt < 31) {
      __syncthreads();
      *reinterpret_cast<bf16x8*>(&Kl[sr][sc4])     = pk0;
      *reinterpret_cast<bf16x8*>(&Kl[sr][sc4 + 8]) = pk1;
      *reinterpret_cast<bf16x8*>(&Vt[sr][sc4])     = pv0;
      *reinterpret_cast<bf16x8*>(&Vt[sr][sc4 + 8]) = pv1;
      if (tid < 16) *reinterpret_cast<ushort4*>(&Vt[64][tid * 4]) = pc;
      __syncthreads();
    }
  }
  // ---- combine key-halves via dedicated Ob (bf16) + lb (fp32) ----
  // accl is a D-tile: c-row product sits in column 0 -> lanes l16==0, rows quad*4+r.
  __syncthreads();
  if (wk == 1) {
#pragma unroll
    for (int u = 0; u < 2; ++u) {
#pragma unroll
      for (int s = 0; s < 4; ++s)
#pragma unroll
        for (int r = 0; r < 4; ++r)
          Ob[(wq * 32 + u * 16 + quad * 4 + r) * 64 + s * 16 + l16] = f2bits(O[u][s][r]);
      if (l16 == 0)
#pragma unroll
        for (int r = 0; r < 4; ++r)
          lb[64 + wq * 32 + u * 16 + quad * 4 + r] = accl[u][r];
    }
  } else {
#pragma unroll
    for (int u = 0; u < 2; ++u)
      if (l16 == 0)
#pragma unroll
        for (int r = 0; r < 4; ++r)
          lb[wq * 32 + u * 16 + quad * 4 + r] = accl[u][r];
  }
  __syncthreads();
  if (wk == 0) {
#pragma unroll
    for (int u = 0; u < 2; ++u)
#pragma unroll
      for (int r = 0; r < 4; ++r) {
        const int ql = wq * 32 + u * 16 + quad * 4 + r;
        const float linv = 1.f / (lb[ql] + lb[64 + ql]);
        const size_t orow = ((size_t)bi * NCTX + qrow0 + ql) * DIMD + hi * DH;
#pragma unroll
        for (int s = 0; s < 4; ++s)
          out[orow + s * 16 + l16] =
              f2bits((O[u][s][r] + bits2f(Ob[ql * 64 + s * 16 + l16])) * linv);
      }
  }
}

extern "C" void kernel_launch(void* const* d_in, const int* in_sizes, int n_in,
                              void* d_out, int out_size, void* d_ws, size_t ws_size,
                              hipStream_t stream) {
  const float* x     = (const float*)d_in[0];
  const float* pose  = (const float*)d_in[1];
  const float* gam   = (const float*)d_in[2];
  const float* bet   = (const float*)d_in[3];
  const float* wqkv  = (const float*)d_in[4];
  const float* wout  = (const float*)d_in[5];
  const float* betap = (const float*)d_in[6];
  float* out = (float*)d_out;

  unsigned short* xn    = (unsigned short*)d_ws;             // 8 MB (reused as aout)
  unsigned short* qkvb  = xn + (size_t)NROWS * DIMD;         // 24 MB
  unsigned short* wqkvT = qkvb + (size_t)NROWS * QKVN;       // 1.5 MB
  unsigned short* woutT = wqkvT + (size_t)QKVN * DIMD;       // 0.5 MB
  unsigned short* vtg   = woutT + (size_t)DIMD * DIMD;       // 8 MB  c-scaled V^T
  unsigned short* cexp  = vtg + (size_t)NB * NH * DH * NCTX; // 16 KB
  unsigned short* aout  = xn;                                // alias: xn dead after GEMM1

  ln_kernel<<<NROWS / 4, 256, 0, stream>>>(x, gam, bet, xn);
  tconv_kernel<<<dim3(QKVN / 64, DIMD / 64, 2), 256, 0, stream>>>(
      wqkv, wqkvT, wout, woutT);
  mgemm_kernel<unsigned short, true><<<dim3(QKVN / 128, NROWS / 128), 256, 0, stream>>>(
      xn, wqkvT, qkvb, NROWS, QKVN, DIMD);
  vtrans_kernel<<<dim3(NCTX / 64, NH, NB), 256, 0, stream>>>(
      qkvb, pose, betap, cexp, vtg);
  fattn_kernel<<<dim3(NCTX / 64, NH, NB), 256, 0, stream>>>(qkvb, vtg, cexp, aout);
  mgemm_kernel<float, false><<<dim3(DIMD / 128, NROWS / 128), 256, 0, stream>>>(
      aout, woutT, out, NROWS, DIMD, DIMD);
}